// Round 2
// baseline (903.010 us; speedup 1.0000x reference)
//
#include <hip/hip_runtime.h>
#include <math.h>

#define PI_F 3.14159265358979323846f

// ---------------------------------------------------------------------------
// Rot coefficient precompute: 72 gates (6 layers x 12 wires), 8 floats each.
// Rot = RZ(om) RY(th) RZ(phi) per PennyLane:
//   u00 = e^{-i(phi+om)/2} cos(th/2)   u01 = -e^{+i(phi-om)/2} sin(th/2)
//   u10 = e^{-i(phi-om)/2} sin(th/2)   u11 = e^{+i(phi+om)/2} cos(th/2)
// ---------------------------------------------------------------------------
__global__ void rot_coef_kernel(const float* __restrict__ weights,
                                float* __restrict__ coef) {
    int g = blockIdx.x * blockDim.x + threadIdx.x;
    if (g < 72) {
        float phi = weights[g * 3 + 0];
        float th  = weights[g * 3 + 1];
        float om  = weights[g * 3 + 2];
        float hs = 0.5f * (phi + om), hd = 0.5f * (phi - om), ht = 0.5f * th;
        float ct = cosf(ht), st = sinf(ht);
        float cs = cosf(hs), ss = sinf(hs);
        float cd = cosf(hd), sd = sinf(hd);
        float* c = coef + g * 8;
        c[0] = cs * ct;  c[1] = -ss * ct;   // u00
        c[2] = -cd * st; c[3] = -sd * st;   // u01
        c[4] = cd * st;  c[5] = -sd * st;   // u10
        c[6] = cs * ct;  c[7] = ss * ct;    // u11
    }
}

// ---------------------------------------------------------------------------
// Layout: ONE WAVE per batch element. 64 complex amps per thread (registers).
// State index i (12 bits), amp i held by lane = i>>6, slot k = i&63.
//   bits 0..5  = k  (in-register)  -> wires 11..6   (wire w <-> bit 11-w)
//   bits 6..11 = lane bits 0..5    -> wires 5..0
// No LDS, no __syncthreads: waves are fully independent.
// ---------------------------------------------------------------------------

template <int B>
__device__ __forceinline__ void rot_gate(float (&re)[64], float (&im)[64],
                                         float r00, float i00, float r01, float i01,
                                         float r10, float i10, float r11, float i11,
                                         int lane) {
    if constexpr (B < 6) {
        constexpr int m = 1 << B;
        #pragma unroll
        for (int k0 = 0; k0 < 64; ++k0) {
            if ((k0 & m) == 0) {
                const int k1 = k0 | m;
                float a0r = re[k0], a0i = im[k0], a1r = re[k1], a1i = im[k1];
                re[k0] = r00 * a0r - i00 * a0i + r01 * a1r - i01 * a1i;
                im[k0] = r00 * a0i + i00 * a0r + r01 * a1i + i01 * a1r;
                re[k1] = r10 * a0r - i10 * a0i + r11 * a1r - i11 * a1i;
                im[k1] = r10 * a0i + i10 * a0r + r11 * a1i + i11 * a1r;
            }
        }
    } else {
        constexpr int lm = 1 << (B - 6);
        const int mybit = (lane >> (B - 6)) & 1;
        const float uar = mybit ? r11 : r00;
        const float uai = mybit ? i11 : i00;
        const float ubr = mybit ? r10 : r01;
        const float ubi = mybit ? i10 : i01;
        #pragma unroll
        for (int k = 0; k < 64; ++k) {
            float pr = __shfl_xor(re[k], lm, 64);
            float pi = __shfl_xor(im[k], lm, 64);
            float r0 = re[k], i0 = im[k];
            re[k] = uar * r0 - uai * i0 + ubr * pr - ubi * pi;
            im[k] = uar * i0 + uai * r0 + ubr * pi + ubi * pr;
        }
    }
}

template <int CB, int TB>
__device__ __forceinline__ void cnot_gate(float (&re)[64], float (&im)[64], int lane) {
    if constexpr (CB < 6 && TB < 6) {
        // static in-register permutation (free after unroll)
        constexpr int cm = 1 << CB, tm = 1 << TB;
        #pragma unroll
        for (int k0 = 0; k0 < 64; ++k0) {
            if ((k0 & cm) && !(k0 & tm)) {
                const int k1 = k0 | tm;
                float tr = re[k0]; re[k0] = re[k1]; re[k1] = tr;
                float ti = im[k0]; im[k0] = im[k1]; im[k1] = ti;
            }
        }
    } else if constexpr (CB < 6) {
        // control local, target lane bit: cross-lane swap of ctrl=1 slots
        constexpr int cm = 1 << CB, lm = 1 << (TB - 6);
        #pragma unroll
        for (int k = 0; k < 64; ++k) {
            if (k & cm) {
                re[k] = __shfl_xor(re[k], lm, 64);
                im[k] = __shfl_xor(im[k], lm, 64);
            }
        }
    } else if constexpr (TB < 6) {
        // control lane bit, target local: per-lane conditional swap (cndmask)
        constexpr int tm = 1 << TB;
        const int cond = (lane >> (CB - 6)) & 1;
        #pragma unroll
        for (int k0 = 0; k0 < 64; ++k0) {
            if (!(k0 & tm)) {
                const int k1 = k0 | tm;
                float r0 = re[k0], i0 = im[k0], r1 = re[k1], i1 = im[k1];
                re[k0] = cond ? r1 : r0; im[k0] = cond ? i1 : i0;
                re[k1] = cond ? r0 : r1; im[k1] = cond ? i0 : i1;
            }
        }
    } else {
        // control lane bit, target lane bit: shuffle with computed source lane
        constexpr int lm = 1 << (TB - 6);
        const int cond = (lane >> (CB - 6)) & 1;
        const int src = cond ? (lane ^ lm) : lane;
        #pragma unroll
        for (int k = 0; k < 64; ++k) {
            re[k] = __shfl(re[k], src, 64);
            im[k] = __shfl(im[k], src, 64);
        }
    }
}

template <bool HC, int W>
__device__ __forceinline__ void layer_rots(float (&re)[64], float (&im)[64],
                                           const float* __restrict__ coef,
                                           const float* __restrict__ wl,
                                           int lane) {
    if constexpr (W < 12) {
        float r00, i00, r01, i01, r10, i10, r11, i11;
        if constexpr (HC) {
            const float* c = coef + W * 8;   // uniform address -> s_load
            r00 = c[0]; i00 = c[1]; r01 = c[2]; i01 = c[3];
            r10 = c[4]; i10 = c[5]; r11 = c[6]; i11 = c[7];
        } else {
            float phi = wl[W * 3 + 0], th = wl[W * 3 + 1], om = wl[W * 3 + 2];
            float hs = 0.5f * (phi + om), hd = 0.5f * (phi - om), ht = 0.5f * th;
            float st, ct, ss, cs, sd, cd;
            __sincosf(ht, &st, &ct);
            __sincosf(hs, &ss, &cs);
            __sincosf(hd, &sd, &cd);
            r00 = cs * ct;  i00 = -ss * ct;
            r01 = -cd * st; i01 = -sd * st;
            r10 = cd * st;  i10 = -sd * st;
            r11 = cs * ct;  i11 = ss * ct;
        }
        rot_gate<11 - W>(re, im, r00, i00, r01, i01, r10, i10, r11, i11, lane);
        layer_rots<HC, W + 1>(re, im, coef, wl, lane);
    }
}

template <int R, int W>
__device__ __forceinline__ void layer_cnots(float (&re)[64], float (&im)[64], int lane) {
    if constexpr (W < 12) {
        cnot_gate<11 - W, 11 - ((W + R) % 12)>(re, im, lane);
        layer_cnots<R, W + 1>(re, im, lane);
    }
}

template <bool HC>
__global__ __launch_bounds__(256) void qvl_main(
    const float* __restrict__ v,        // (B, 512)
    const float* __restrict__ Wc,       // (12, 512)
    const float* __restrict__ bc,       // (12,)
    const float* __restrict__ weights,  // (6, 12, 3)
    const float* __restrict__ coef,     // (72, 8) or unused
    float* __restrict__ out,            // (B, 12)
    int Btot)
{
    const int t    = threadIdx.x;
    const int lane = t & 63;
    const int wave = t >> 6;
    const int b    = blockIdx.x * 4 + wave;
    if (b >= Btot) return;   // whole-wave uniform; no barriers anywhere

    // ---- x_w = tanh(v[b] . Wc[w] + bc[w]) * pi ; se/ce = sin/cos(x/2) ------
    float ce[12], se[12];
    {
        const float4* vp = reinterpret_cast<const float4*>(v + b * 512);
        const float4 v0 = vp[lane * 2], v1 = vp[lane * 2 + 1];
        #pragma unroll
        for (int w = 0; w < 12; ++w) {
            const float4* wp = reinterpret_cast<const float4*>(Wc + w * 512);
            const float4 w0 = wp[lane * 2], w1 = wp[lane * 2 + 1];
            float p = v0.x * w0.x + v0.y * w0.y + v0.z * w0.z + v0.w * w0.w
                    + v1.x * w1.x + v1.y * w1.y + v1.z * w1.z + v1.w * w1.w;
            #pragma unroll
            for (int s = 1; s < 64; s <<= 1) p += __shfl_xor(p, s, 64);
            float x = tanhf(p + bc[w]) * PI_F;
            float h = 0.5f * x;
            se[w] = sinf(h);
            ce[w] = cosf(h);
        }
    }

    // ---- AngleEmbedding(RY) as a direct product state ----------------------
    // amp bit b set -> sin factor of wire 11-b.
    // lane bit j -> wire 5-j ; k bit j -> wire 11-j
    float fl = 1.0f;
    fl *= (lane & 1)  ? se[5] : ce[5];
    fl *= (lane & 2)  ? se[4] : ce[4];
    fl *= (lane & 4)  ? se[3] : ce[3];
    fl *= (lane & 8)  ? se[2] : ce[2];
    fl *= (lane & 16) ? se[1] : ce[1];
    fl *= (lane & 32) ? se[0] : ce[0];
    float f01[4], f23[4], f45[4];
    #pragma unroll
    for (int m = 0; m < 4; ++m) {
        f01[m] = ((m & 1) ? se[11] : ce[11]) * ((m & 2) ? se[10] : ce[10]);
        f23[m] = ((m & 1) ? se[9]  : ce[9])  * ((m & 2) ? se[8]  : ce[8]);
        f45[m] = ((m & 1) ? se[7]  : ce[7])  * ((m & 2) ? se[6]  : ce[6]);
    }
    float re[64], im[64];
    #pragma unroll
    for (int k = 0; k < 64; ++k) {
        re[k] = fl * f01[k & 3] * f23[(k >> 2) & 3] * f45[(k >> 4) & 3];
        im[k] = 0.0f;
    }

    // ---- 6 StronglyEntanglingLayers ----------------------------------------
    #pragma unroll 1
    for (int l = 0; l < 6; ++l) {
        layer_rots<HC, 0>(re, im, coef + l * 96, weights + l * 36, lane);
        switch (l) {  // r = l + 1
            case 0: layer_cnots<1, 0>(re, im, lane); break;
            case 1: layer_cnots<2, 0>(re, im, lane); break;
            case 2: layer_cnots<3, 0>(re, im, lane); break;
            case 3: layer_cnots<4, 0>(re, im, lane); break;
            case 4: layer_cnots<5, 0>(re, im, lane); break;
            case 5: layer_cnots<6, 0>(re, im, lane); break;
        }
    }

    // ---- PauliZ expvals -----------------------------------------------------
    float z[12];
    float tot = 0.0f;
    float zk0 = 0.0f, zk1 = 0.0f, zk2 = 0.0f, zk3 = 0.0f, zk4 = 0.0f, zk5 = 0.0f;
    #pragma unroll
    for (int k = 0; k < 64; ++k) {
        float p = re[k] * re[k] + im[k] * im[k];
        tot += p;
        zk0 += (k & 1)  ? -p : p;   // wire 11
        zk1 += (k & 2)  ? -p : p;   // wire 10
        zk2 += (k & 4)  ? -p : p;   // wire 9
        zk3 += (k & 8)  ? -p : p;   // wire 8
        zk4 += (k & 16) ? -p : p;   // wire 7
        zk5 += (k & 32) ? -p : p;   // wire 6
    }
    z[11] = zk0; z[10] = zk1; z[9] = zk2; z[8] = zk3; z[7] = zk4; z[6] = zk5;
    z[5] = (lane & 1)  ? -tot : tot;
    z[4] = (lane & 2)  ? -tot : tot;
    z[3] = (lane & 4)  ? -tot : tot;
    z[2] = (lane & 8)  ? -tot : tot;
    z[1] = (lane & 16) ? -tot : tot;
    z[0] = (lane & 32) ? -tot : tot;
    #pragma unroll
    for (int w = 0; w < 12; ++w) {
        #pragma unroll
        for (int s = 1; s < 64; s <<= 1) z[w] += __shfl_xor(z[w], s, 64);
    }
    if (lane == 0) {
        #pragma unroll
        for (int w = 0; w < 12; ++w) out[b * 12 + w] = z[w];
    }
}

extern "C" void kernel_launch(void* const* d_in, const int* in_sizes, int n_in,
                              void* d_out, int out_size, void* d_ws, size_t ws_size,
                              hipStream_t stream) {
    (void)n_in; (void)out_size;
    const float* v   = (const float*)d_in[0];
    const float* Wc  = (const float*)d_in[1];
    const float* bc  = (const float*)d_in[2];
    const float* wts = (const float*)d_in[3];
    float* out = (float*)d_out;

    const int B = in_sizes[0] / 512;
    const int nblk = (B + 3) / 4;

    if (d_ws && ws_size >= 72 * 8 * sizeof(float)) {
        float* coef = (float*)d_ws;
        rot_coef_kernel<<<1, 128, 0, stream>>>(wts, coef);
        qvl_main<true><<<nblk, 256, 0, stream>>>(v, Wc, bc, wts, coef, out, B);
    } else {
        qvl_main<false><<<nblk, 256, 0, stream>>>(v, Wc, bc, wts, (const float*)nullptr, out, B);
    }
}

// Round 3
// 538.538 us; speedup vs baseline: 1.6768x; 1.6768x over previous
//
#include <hip/hip_runtime.h>
#include <math.h>

#define PI_F 3.14159265358979323846f

// ---------------------------------------------------------------------------
// GF(2) deferred-CNOT bookkeeping, computed at COMPILE TIME.
// Physical index p (12 bits, bit b <-> wire 11-b initially). M maps logical
// index -> physical slot; amp_phys[M i] = psi[i]. CNOT(c,t): M <- M*E =>
// col[c] ^= col[t]; M^-1 rows: r[t] ^= r[c]. Rot on logical wire w pairs
// p <-> p^m (m = col[w]) with role bit = parity(p & r[w]). Guaranteed
// parity(m & r) == 1. Z expval wire w: sign = parity(p & zrow[w]).
// ---------------------------------------------------------------------------
struct GateTab {
    unsigned mask[72];   // pairing XOR mask per gate
    unsigned role[72];   // role parity row per gate
    unsigned zrow[12];   // final measurement parity rows
};

constexpr GateTab make_tab() {
    GateTab tb{};
    unsigned col[12], row[12];
    for (int w = 0; w < 12; ++w) { col[w] = 1u << (11 - w); row[w] = 1u << (11 - w); }
    for (int l = 0; l < 6; ++l) {
        for (int w = 0; w < 12; ++w) {
            tb.mask[l * 12 + w] = col[w];
            tb.role[l * 12 + w] = row[w];
        }
        const int r = l + 1;
        for (int w = 0; w < 12; ++w) {
            const int c = w, tg = (w + r) % 12;
            col[c] ^= col[tg];     // M <- M * E(c,t)
            row[tg] ^= row[c];     // M^-1 <- E(c,t) * M^-1
        }
    }
    for (int w = 0; w < 12; ++w) tb.zrow[w] = row[w];
    return tb;
}

__constant__ GateTab GT = make_tab();

// ---------------------------------------------------------------------------
// One block (256 threads) per batch element. State float2 st[4096] in LDS.
// Rolled 72-gate loop; per gate each thread owns 8 disjoint pairs.
// Representative p has parity(p & r) == 0 (role 0), so coefficients need no
// per-pair selection: na = u00*a + u01*b ; nb = u10*a + u11*b.
// ---------------------------------------------------------------------------
__global__ __launch_bounds__(256) void qvl_lds(
    const float* __restrict__ v,        // (B, 512)
    const float* __restrict__ Wc,       // (12, 512)
    const float* __restrict__ bc,       // (12,)
    const float* __restrict__ weights,  // (6, 12, 3)
    float* __restrict__ out)            // (B, 12)
{
    __shared__ float2 st[4096];     // 32 KB state
    __shared__ float  ctab[72][8];  // Rot coefficients
    __shared__ float  red[12][4];
    __shared__ float  ses[12], ces[12];

    const int t    = threadIdx.x;
    const int lane = t & 63;
    const int wv   = t >> 6;
    const int b    = blockIdx.x;

    // ---- Rot coefficient table (batch-independent; redundant per block) ----
    if (t < 72) {
        const float phi = weights[t * 3 + 0];
        const float th  = weights[t * 3 + 1];
        const float om  = weights[t * 3 + 2];
        const float hs = 0.5f * (phi + om), hd = 0.5f * (phi - om), ht = 0.5f * th;
        const float ctt = cosf(ht), stt = sinf(ht);
        const float cs = cosf(hs), ss = sinf(hs);
        const float cd = cosf(hd), sd = sinf(hd);
        ctab[t][0] = cs * ctt;  ctab[t][1] = -ss * ctt;   // u00
        ctab[t][2] = -cd * stt; ctab[t][3] = -sd * stt;   // u01
        ctab[t][4] = cd * stt;  ctab[t][5] = -sd * stt;   // u10
        ctab[t][6] = cs * ctt;  ctab[t][7] = ss * ctt;    // u11
    }

    // ---- x_w = tanh(v[b] . Wc[w] + bc[w]) * pi -----------------------------
    {
        const float2 vv = reinterpret_cast<const float2*>(v + b * 512)[t];
        #pragma unroll
        for (int w = 0; w < 12; ++w) {
            const float2 ww = reinterpret_cast<const float2*>(Wc + w * 512)[t];
            float p = vv.x * ww.x + vv.y * ww.y;
            #pragma unroll
            for (int s = 1; s < 64; s <<= 1) p += __shfl_xor(p, s, 64);
            if (lane == 0) red[w][wv] = p;
        }
    }
    __syncthreads();
    if (t < 12) {
        const float x = tanhf(red[t][0] + red[t][1] + red[t][2] + red[t][3] + bc[t]) * PI_F;
        const float h = 0.5f * x;
        ses[t] = sinf(h);
        ces[t] = cosf(h);
    }
    __syncthreads();

    // ---- product state init (M = I): bit b of p set -> sin of wire 11-b ----
    {
        float hi = 1.0f;                       // p bits 4..11 = t bits 0..7
        hi *= (t & 1)   ? ses[7] : ces[7];
        hi *= (t & 2)   ? ses[6] : ces[6];
        hi *= (t & 4)   ? ses[5] : ces[5];
        hi *= (t & 8)   ? ses[4] : ces[4];
        hi *= (t & 16)  ? ses[3] : ces[3];
        hi *= (t & 32)  ? ses[2] : ces[2];
        hi *= (t & 64)  ? ses[1] : ces[1];
        hi *= (t & 128) ? ses[0] : ces[0];
        float f01[4], f23[4];
        #pragma unroll
        for (int m = 0; m < 4; ++m) {
            f01[m] = ((m & 1) ? ses[11] : ces[11]) * ((m & 2) ? ses[10] : ces[10]);
            f23[m] = ((m & 1) ? ses[9]  : ces[9])  * ((m & 2) ? ses[8]  : ces[8]);
        }
        #pragma unroll
        for (int k = 0; k < 16; ++k)
            st[t * 16 + k] = make_float2(hi * f01[k & 3] * f23[k >> 2], 0.0f);
    }

    // ---- 72 generalized butterflies (CNOTs are free bookkeeping) -----------
    #pragma unroll 1
    for (int g = 0; g < 72; ++g) {
        __syncthreads();   // previous gate's writes / state init -> this gate's reads
        const unsigned m   = GT.mask[g];
        const unsigned r   = GT.role[g];
        const unsigned hb  = r & (0u - r);     // lowest set bit of r
        const unsigned hm1 = hb - 1u;
        const float u00r = ctab[g][0], u00i = ctab[g][1];
        const float u01r = ctab[g][2], u01i = ctab[g][3];
        const float u10r = ctab[g][4], u10i = ctab[g][5];
        const float u11r = ctab[g][6], u11i = ctab[g][7];
        #pragma unroll
        for (int jj = 0; jj < 8; ++jj) {
            const unsigned j   = (unsigned)(jj * 256 + t);
            const unsigned low = j & hm1;
            const unsigned q   = (j << 1) - low;          // insert 0 at bit h
            const unsigned par = __popc(q & r) & 1u;
            const unsigned p0  = q | (par ? hb : 0u);     // parity(p0 & r) == 0
            const unsigned p1  = p0 ^ m;
            const float2 a  = st[p0];
            const float2 bb = st[p1];
            float2 na, nb;
            na.x = u00r * a.x - u00i * a.y + u01r * bb.x - u01i * bb.y;
            na.y = u00r * a.y + u00i * a.x + u01r * bb.y + u01i * bb.x;
            nb.x = u10r * a.x - u10i * a.y + u11r * bb.x - u11i * bb.y;
            nb.y = u10r * a.y + u10i * a.x + u11r * bb.y + u11i * bb.x;
            st[p0] = na;
            st[p1] = nb;
        }
    }
    __syncthreads();

    // ---- PauliZ expvals with final GF(2) rows ------------------------------
    float p2[16];
    #pragma unroll
    for (int k = 0; k < 16; ++k) {
        const float2 aa = st[t * 16 + k];
        p2[k] = aa.x * aa.x + aa.y * aa.y;
    }
    #pragma unroll
    for (int w = 0; w < 12; ++w) {
        const unsigned zr = GT.zrow[w];
        const unsigned Aw = __popc((unsigned)(t << 4) & zr) & 1u;
        const unsigned nm = zr & 15u;
        unsigned P = 0u;                       // bit k = parity(p & zr) for p = t*16+k
        P ^= (nm & 1u) ? 0xAAAAu : 0u;
        P ^= (nm & 2u) ? 0xCCCCu : 0u;
        P ^= (nm & 4u) ? 0xF0F0u : 0u;
        P ^= (nm & 8u) ? 0xFF00u : 0u;
        P ^= Aw ? 0xFFFFu : 0u;
        float z = 0.0f;
        #pragma unroll
        for (int k = 0; k < 16; ++k)
            z += ((P >> k) & 1u) ? -p2[k] : p2[k];
        #pragma unroll
        for (int s = 1; s < 64; s <<= 1) z += __shfl_xor(z, s, 64);
        if (lane == 0) red[w][wv] = z;
    }
    __syncthreads();
    if (t < 12)
        out[b * 12 + t] = red[t][0] + red[t][1] + red[t][2] + red[t][3];
}

extern "C" void kernel_launch(void* const* d_in, const int* in_sizes, int n_in,
                              void* d_out, int out_size, void* d_ws, size_t ws_size,
                              hipStream_t stream) {
    (void)n_in; (void)out_size; (void)d_ws; (void)ws_size;
    const float* v   = (const float*)d_in[0];
    const float* Wc  = (const float*)d_in[1];
    const float* bc  = (const float*)d_in[2];
    const float* wts = (const float*)d_in[3];
    float* out = (float*)d_out;

    const int B = in_sizes[0] / 512;
    qvl_lds<<<B, 256, 0, stream>>>(v, Wc, bc, wts, out);
}